// Round 3
// baseline (286.442 us; speedup 1.0000x reference)
//
#include <hip/hip_runtime.h>
#include <hip/hip_bf16.h>

// Problem constants: B=8, IN_C=64, H=W=32, NH=8, dkh=dvh=8, OUT_C=128.
// Inputs: float32 storage (verified: bf16-decode of x gives inf-scale garbage).
// Output: float32 (reference output dtype is float32).
// k_prep keeps a storage sniff (f32 vs bf16) as a robustness hedge.

// ---- workspace layout (float32 element offsets) ----
constexpr int XPAD  = 0;                       // padded x: [8][64][34][34]
constexpr int NXPAD = 8 * 64 * 34 * 34;        // 591872
constexpr int WQKV  = NXPAD;                   // [192][64]        12288
constexpr int WCONV = WQKV + 12288;            // [64][64][9]      36864
constexpr int WATTN = WCONV + 36864;           // [64][64]          4096
constexpr int BQKV  = WATTN + 4096;            // 192
constexpr int BCONV = BQKV + 192;              // 64
constexpr int BATTN = BCONV + 64;              // 64
constexpr int RELW  = BATTN + 64;              // [63][8]           504
constexpr int RELH  = RELW + 504;              // [63][8]           504
constexpr int WEND  = RELH + 504;              // 646448 (16B aligned)
constexpr int QBUF  = WEND;                    // [64 bn][1024][8]  524288 (q pre-scaled)
constexpr int KVBUF = QBUF + 524288;           // [64 bn][1024][16] (k|v interleaved) 1048576
constexpr int APRE  = KVBUF + 1048576;         // [8][64][1024]     524288
// total = 2743600 floats = ~10.5 MB

__device__ __forceinline__ float load_in(const void* p, int i, bool f32mode) {
    return f32mode ? ((const float*)p)[i]
                   : __bfloat162float(((const __hip_bfloat16*)p)[i]);
}

// ---------------------------------------------------------------------------
// Kernel 0: upcast all params to f32 in ws; build zero-padded f32 x.
// ---------------------------------------------------------------------------
__global__ __launch_bounds__(256) void k_prep(
    const void* __restrict__ x,
    const void* __restrict__ conv_w,
    const void* __restrict__ conv_b,
    const void* __restrict__ qkv_w,
    const void* __restrict__ qkv_b,
    const void* __restrict__ attn_w,
    const void* __restrict__ attn_b,
    const void* __restrict__ rel_w,
    const void* __restrict__ rel_h,
    float* __restrict__ ws)
{
    // Storage-dtype sniff: decode first 128 halfwords of x as bf16. If storage
    // is f32, low-half mantissa bits decode to huge magnitudes (random exponent
    // field) with overwhelming probability; genuine bf16 N(0,1) stays < ~6.
    const __hip_bfloat16* xh = (const __hip_bfloat16*)x;
    bool f32mode = false;
    #pragma unroll
    for (int i = 0; i < 128; ++i) {
        float v = __bfloat162float(xh[i]);
        if (v > 1e3f || v < -1e3f) f32mode = true;
    }

    int idx = blockIdx.x * 256 + threadIdx.x;
    if (idx < NXPAD) {
        int bc = idx / 1156, r = idx % 1156;
        int hh = r / 34 - 1, ww = r % 34 - 1;
        float v = 0.f;
        if ((unsigned)hh < 32u && (unsigned)ww < 32u)
            v = load_in(x, bc * 1024 + hh * 32 + ww, f32mode);
        ws[XPAD + idx] = v;
    } else if (idx < WEND) {
        int w1 = idx - NXPAD;
        float v; int dst;
        if      (w1 < 12288) { v = load_in(qkv_w,  w1,          f32mode); dst = WQKV  + w1; }
        else if (w1 < 49152) { v = load_in(conv_w, w1 - 12288,  f32mode); dst = WCONV + w1 - 12288; }
        else if (w1 < 53248) { v = load_in(attn_w, w1 - 49152,  f32mode); dst = WATTN + w1 - 49152; }
        else if (w1 < 53440) { v = load_in(qkv_b,  w1 - 53248,  f32mode); dst = BQKV  + w1 - 53248; }
        else if (w1 < 53504) { v = load_in(conv_b, w1 - 53440,  f32mode); dst = BCONV + w1 - 53440; }
        else if (w1 < 53568) { v = load_in(attn_b, w1 - 53504,  f32mode); dst = BATTN + w1 - 53504; }
        else if (w1 < 54072) { v = load_in(rel_w,  w1 - 53568,  f32mode); dst = RELW  + w1 - 53568; }
        else                 { v = load_in(rel_h,  w1 - 54072,  f32mode); dst = RELH  + w1 - 54072; }
        ws[dst] = v;
    }
}

// ---------------------------------------------------------------------------
// Kernel 1: qkv 1x1 conv. grid = 8(b) x 4(pos chunk) x 8(out group of 24).
// Weights read at wave-uniform addresses (s_load), x row held in 64 VGPRs.
// Q stored scaled by dkh^-0.5; K/V interleaved 16 floats per (bn, j).
// ---------------------------------------------------------------------------
__global__ __launch_bounds__(256) void k_qkv(
    const float* __restrict__ xpad,
    const float* __restrict__ wq,
    const float* __restrict__ bq,
    float* __restrict__ qbuf,
    float* __restrict__ kvbuf)
{
    int blk = blockIdx.x;
    int b = blk >> 5, rem = blk & 31, pc = rem >> 3, og = rem & 7;
    int p = pc * 256 + threadIdx.x;        // 0..1023
    int h = p >> 5, w = p & 31;
    const float* xb = xpad + (b * 64) * 1156 + (h + 1) * 34 + (w + 1);
    float xr[64];
    #pragma unroll
    for (int c = 0; c < 64; ++c) xr[c] = xb[c * 1156];

    #pragma unroll 4
    for (int oo = 0; oo < 24; ++oo) {
        int o = og * 24 + oo;              // 0..191, wave-uniform
        const float* wr = wq + o * 64;
        float acc = bq[o];
        #pragma unroll
        for (int c = 0; c < 64; ++c) acc = fmaf(wr[c], xr[c], acc);
        if (o < 64) {
            qbuf[((b * 8 + (o >> 3)) * 1024 + p) * 8 + (o & 7)] = acc * 0.35355339059327373f;
        } else if (o < 128) {
            int k = o - 64;
            kvbuf[((b * 8 + (k >> 3)) * 1024 + p) * 16 + (k & 7)] = acc;
        } else {
            int k = o - 128;
            kvbuf[((b * 8 + (k >> 3)) * 1024 + p) * 16 + 8 + (k & 7)] = acc;
        }
    }
}

// ---------------------------------------------------------------------------
// Kernel 2: attention. grid = 64(bn) x 8(query chunk of 128) blocks, 256 thr.
// Thread pair (tid, tid+128) shares query iq, splits keys [0,512)/[512,1024).
// No-max softmax (logits are O(+-3), exp-safe in f32) -> partials merge by sum.
// Aw/Ah per-thread tables live in LDS at [idx*256+tid] (stride-1, no conflicts,
// avoids dynamic register indexing -> scratch).
// ---------------------------------------------------------------------------
__global__ __launch_bounds__(256) void k_attn(
    const float* __restrict__ qbuf,
    const float* __restrict__ kvbuf,
    const float* __restrict__ relw,
    const float* __restrict__ relh,
    float* __restrict__ apre)
{
    __shared__ float lAw[32 * 256];
    __shared__ float lAh[32 * 256];

    int blk = blockIdx.x;
    int bn = blk >> 3, qc = blk & 7;
    int tid = threadIdx.x;
    int lane = tid & 127, jh = tid >> 7;
    int iq = qc * 128 + lane;
    int h = iq >> 5, w = iq & 31;

    const float* qp = qbuf + (bn * 1024 + iq) * 8;
    float4 qa = *(const float4*)qp;
    float4 qb = *(const float4*)(qp + 4);

    #pragma unroll 4
    for (int t = 0; t < 32; ++t) {
        const float* rw = relw + (t - w + 31) * 8;
        lAw[t * 256 + tid] =
            qa.x * rw[0] + qa.y * rw[1] + qa.z * rw[2] + qa.w * rw[3] +
            qb.x * rw[4] + qb.y * rw[5] + qb.z * rw[6] + qb.w * rw[7];
        const float* rh = relh + (t - h + 31) * 8;
        lAh[t * 256 + tid] =
            qa.x * rh[0] + qa.y * rh[1] + qa.z * rh[2] + qa.w * rh[3] +
            qb.x * rh[4] + qb.y * rh[5] + qb.z * rh[6] + qb.w * rh[7];
    }

    float a0 = 0.f, a1 = 0.f, a2 = 0.f, a3 = 0.f;
    float a4 = 0.f, a5 = 0.f, a6 = 0.f, a7 = 0.f;
    float l = 0.f;
    const float* kv = kvbuf + bn * (1024 * 16) + jh * (512 * 16);

    for (int jj = 0; jj < 512; ++jj) {
        const float* row = kv + jj * 16;   // wave-uniform address -> s_load
        float4 ka = *(const float4*)row;
        float4 kb = *(const float4*)(row + 4);
        int j = (jh << 9) + jj;
        float s = lAw[(j & 31) * 256 + tid] + lAh[(j >> 5) * 256 + tid];
        s += qa.x * ka.x + qa.y * ka.y + qa.z * ka.z + qa.w * ka.w +
             qb.x * kb.x + qb.y * kb.y + qb.z * kb.z + qb.w * kb.w;
        float pe = __expf(s);
        l += pe;
        float4 va = *(const float4*)(row + 8);
        float4 vb = *(const float4*)(row + 12);
        a0 = fmaf(pe, va.x, a0); a1 = fmaf(pe, va.y, a1);
        a2 = fmaf(pe, va.z, a2); a3 = fmaf(pe, va.w, a3);
        a4 = fmaf(pe, vb.x, a4); a5 = fmaf(pe, vb.y, a5);
        a6 = fmaf(pe, vb.z, a6); a7 = fmaf(pe, vb.w, a7);
    }

    // Reduce the two key-halves. Reuse lAw; each thread only touches column tid
    // (same congruence class it read), so no pre-store barrier is needed.
    float* red = lAw;
    red[0 * 256 + tid] = a0; red[1 * 256 + tid] = a1;
    red[2 * 256 + tid] = a2; red[3 * 256 + tid] = a3;
    red[4 * 256 + tid] = a4; red[5 * 256 + tid] = a5;
    red[6 * 256 + tid] = a6; red[7 * 256 + tid] = a7;
    red[8 * 256 + tid] = l;
    __syncthreads();

    if (tid < 128) {
        int b = bn >> 3, n = bn & 7;
        float li = red[8 * 256 + tid] + red[8 * 256 + tid + 128];
        float inv = 1.0f / li;
        float* ap = apre + (b * 64 + n * 8) * 1024 + qc * 128 + tid;
        #pragma unroll
        for (int d = 0; d < 8; ++d) {
            float av = red[d * 256 + tid] + red[d * 256 + tid + 128];
            ap[d * 1024] = av * inv;
        }
    }
}

// ---------------------------------------------------------------------------
// Kernel 3: fused output (float32 out). grid = 8(b) x 4(row group) x 16(role):
// role 0..7  -> 3x3 conv, output channels role*8..role*8+7
// role 8..15 -> attn 1x1 projection, output channels 64 + (role-8)*8 ...
// ---------------------------------------------------------------------------
__global__ __launch_bounds__(256) void k_out(
    const float* __restrict__ xpad,
    const float* __restrict__ wconv,
    const float* __restrict__ bconv,
    const float* __restrict__ wattn,
    const float* __restrict__ battn,
    const float* __restrict__ apre,
    float* __restrict__ out)
{
    int blk = blockIdx.x;
    int b = blk >> 6, rem = blk & 63, rg = rem >> 4, og = rem & 15;
    int tid = threadIdx.x;
    int p = rg * 256 + tid;                 // 0..1023
    float acc[8];

    if (og < 8) {
        int oc0 = og * 8;
        #pragma unroll
        for (int g = 0; g < 8; ++g) acc[g] = bconv[oc0 + g];
        int row = p >> 5, col = p & 31;
        const float* xb = xpad + b * 64 * 1156 + row * 34 + col;
        for (int c = 0; c < 64; ++c) {
            const float* xc = xb + c * 1156;
            float xv[9];
            #pragma unroll
            for (int t = 0; t < 9; ++t) xv[t] = xc[(t / 3) * 34 + (t % 3)];
            const float* wc = wconv + (oc0 * 64 + c) * 9;   // uniform -> s_load
            #pragma unroll
            for (int g = 0; g < 8; ++g) {
                #pragma unroll
                for (int t = 0; t < 9; ++t)
                    acc[g] = fmaf(wc[g * 576 + t], xv[t], acc[g]);
            }
        }
        #pragma unroll
        for (int g = 0; g < 8; ++g)
            out[(b * 128 + oc0 + g) * 1024 + p] = acc[g];
    } else {
        int o0 = (og - 8) * 8;
        #pragma unroll
        for (int g = 0; g < 8; ++g) acc[g] = battn[o0 + g];
        const float* ap = apre + b * 64 * 1024 + p;
        for (int c = 0; c < 64; ++c) {
            float xv = ap[c * 1024];
            #pragma unroll
            for (int g = 0; g < 8; ++g)
                acc[g] = fmaf(wattn[(o0 + g) * 64 + c], xv, acc[g]);
        }
        #pragma unroll
        for (int g = 0; g < 8; ++g)
            out[(b * 128 + 64 + o0 + g) * 1024 + p] = acc[g];
    }
}

// ---------------------------------------------------------------------------
extern "C" void kernel_launch(void* const* d_in, const int* in_sizes, int n_in,
                              void* d_out, int out_size, void* d_ws, size_t ws_size,
                              hipStream_t stream)
{
    float* ws = (float*)d_ws;
    float* out = (float*)d_out;

    k_prep<<<(WEND + 255) / 256, 256, 0, stream>>>(
        d_in[0], d_in[1], d_in[2], d_in[3], d_in[4],
        d_in[5], d_in[6], d_in[7], d_in[8], ws);
    k_qkv<<<256, 256, 0, stream>>>(
        ws + XPAD, ws + WQKV, ws + BQKV, ws + QBUF, ws + KVBUF);
    k_attn<<<512, 256, 0, stream>>>(
        ws + QBUF, ws + KVBUF, ws + RELW, ws + RELH, ws + APRE);
    k_out<<<512, 256, 0, stream>>>(
        ws + XPAD, ws + WCONV, ws + BCONV, ws + WATTN, ws + BATTN, ws + APRE, out);
}

// Round 5
// 259.165 us; speedup vs baseline: 1.1053x; 1.1053x over previous
//
#include <hip/hip_runtime.h>
#include <hip/hip_bf16.h>

// Problem constants: B=8, IN_C=64, H=W=32, NH=8, dkh=dvh=8, OUT_C=128.
// Inputs: float32 storage (verified R1/R2). Output: float32.

// ---- workspace layout (float32 element offsets) ----
constexpr int XPAD  = 0;                       // padded x: [8][64][34][34]
constexpr int NXPAD = 8 * 64 * 34 * 34;        // 591872
constexpr int WQKV  = NXPAD;                   // [192][64]        12288
constexpr int WCONV = WQKV + 12288;            // [64][64][9]      36864
constexpr int WATTN = WCONV + 36864;           // [64][64]          4096
constexpr int BQKV  = WATTN + 4096;            // 192
constexpr int BCONV = BQKV + 192;              // 64
constexpr int BATTN = BCONV + 64;              // 64
constexpr int RELW  = BATTN + 64;              // [63][8]           504
constexpr int RELH  = RELW + 504;              // [63][8]           504
constexpr int WEND  = RELH + 504;              // 646448
constexpr int QBUF  = WEND;                    // [64 bn][1024][8]  (q pre-scaled)
constexpr int KVBUF = QBUF + 524288;           // [64 bn][1024][16] (k|v interleaved)
constexpr int APRE  = KVBUF + 1048576;         // [8][64][1024]
// total = 2743600 floats = ~10.5 MB

__device__ __forceinline__ float load_in(const void* p, int i, bool f32mode) {
    return f32mode ? ((const float*)p)[i]
                   : __bfloat162float(((const __hip_bfloat16*)p)[i]);
}

// ---------------------------------------------------------------------------
// Kernel 0: upcast all params to f32 in ws; build zero-padded f32 x.
// ---------------------------------------------------------------------------
__global__ __launch_bounds__(256) void k_prep(
    const void* __restrict__ x,
    const void* __restrict__ conv_w,
    const void* __restrict__ conv_b,
    const void* __restrict__ qkv_w,
    const void* __restrict__ qkv_b,
    const void* __restrict__ attn_w,
    const void* __restrict__ attn_b,
    const void* __restrict__ rel_w,
    const void* __restrict__ rel_h,
    float* __restrict__ ws)
{
    // Storage-dtype sniff (hedge): f32 storage decoded as bf16 gives huge values.
    const __hip_bfloat16* xh = (const __hip_bfloat16*)x;
    bool f32mode = false;
    #pragma unroll
    for (int i = 0; i < 128; ++i) {
        float v = __bfloat162float(xh[i]);
        if (v > 1e3f || v < -1e3f) f32mode = true;
    }

    int idx = blockIdx.x * 256 + threadIdx.x;
    if (idx < NXPAD) {
        int bc = idx / 1156, r = idx % 1156;
        int hh = r / 34 - 1, ww = r % 34 - 1;
        float v = 0.f;
        if ((unsigned)hh < 32u && (unsigned)ww < 32u)
            v = load_in(x, bc * 1024 + hh * 32 + ww, f32mode);
        ws[XPAD + idx] = v;
    } else if (idx < WEND) {
        int w1 = idx - NXPAD;
        float v; int dst;
        if      (w1 < 12288) { v = load_in(qkv_w,  w1,          f32mode); dst = WQKV  + w1; }
        else if (w1 < 49152) { v = load_in(conv_w, w1 - 12288,  f32mode); dst = WCONV + w1 - 12288; }
        else if (w1 < 53248) { v = load_in(attn_w, w1 - 49152,  f32mode); dst = WATTN + w1 - 49152; }
        else if (w1 < 53440) { v = load_in(qkv_b,  w1 - 53248,  f32mode); dst = BQKV  + w1 - 53248; }
        else if (w1 < 53504) { v = load_in(conv_b, w1 - 53440,  f32mode); dst = BCONV + w1 - 53440; }
        else if (w1 < 53568) { v = load_in(attn_b, w1 - 53504,  f32mode); dst = BATTN + w1 - 53504; }
        else if (w1 < 54072) { v = load_in(rel_w,  w1 - 53568,  f32mode); dst = RELW  + w1 - 53568; }
        else                 { v = load_in(rel_h,  w1 - 54072,  f32mode); dst = RELH  + w1 - 54072; }
        ws[dst] = v;
    }
}

// ---------------------------------------------------------------------------
// Kernel 1: qkv 1x1 conv. grid = 8(b) x 4(pos chunk) x 16(out group of 12)
// = 512 blocks (2/CU). Weights wave-uniform (s_load); x row in VGPRs.
// ---------------------------------------------------------------------------
__global__ __launch_bounds__(256) void k_qkv(
    const float* __restrict__ xpad,
    const float* __restrict__ wq,
    const float* __restrict__ bq,
    float* __restrict__ qbuf,
    float* __restrict__ kvbuf)
{
    int blk = blockIdx.x;
    int b = blk >> 6, rem = blk & 63, pc = rem >> 4, og = rem & 15;
    int p = pc * 256 + threadIdx.x;        // 0..1023
    int h = p >> 5, w = p & 31;
    const float* xb = xpad + (b * 64) * 1156 + (h + 1) * 34 + (w + 1);
    float xr[64];
    #pragma unroll
    for (int c = 0; c < 64; ++c) xr[c] = xb[c * 1156];

    #pragma unroll 4
    for (int oo = 0; oo < 12; ++oo) {
        int o = og * 12 + oo;              // 0..191, wave-uniform
        const float* wr = wq + o * 64;
        float acc = bq[o];
        #pragma unroll
        for (int c = 0; c < 64; ++c) acc = fmaf(wr[c], xr[c], acc);
        if (o < 64) {
            qbuf[((b * 8 + (o >> 3)) * 1024 + p) * 8 + (o & 7)] = acc * 0.35355339059327373f;
        } else if (o < 128) {
            int k = o - 64;
            kvbuf[((b * 8 + (k >> 3)) * 1024 + p) * 16 + (k & 7)] = acc;
        } else {
            int k = o - 128;
            kvbuf[((b * 8 + (k >> 3)) * 1024 + p) * 16 + 8 + (k & 7)] = acc;
        }
    }
}

// ---------------------------------------------------------------------------
// Kernel 2: attention. grid = 64(bn) x 16(query chunk of 64) = 1024 blocks
// (4/CU). 256 threads: tid = q(0..63) + 64*quad(0..3); the 4 quads split the
// 1024 keys into 256-key quarters (wave == quad, so KV rows are wave-uniform
// broadcast loads). Aw/Ah tables deduplicated per query: [32][64] each
// (16 KB), reduction buffer 9 KB -> 25 KB LDS total, not occupancy-binding.
// No-max softmax (logits O(+-3)) -> quad partials merge by plain sum.
// ---------------------------------------------------------------------------
__global__ __launch_bounds__(256) void k_attn(
    const float* __restrict__ qbuf,
    const float* __restrict__ kvbuf,
    const float* __restrict__ relw,
    const float* __restrict__ relh,
    float* __restrict__ apre)
{
    __shared__ float lAw[32 * 64];
    __shared__ float lAh[32 * 64];
    __shared__ float red[9 * 256];

    int blk = blockIdx.x;
    int bn = blk >> 4, qc = blk & 15;
    int tid = threadIdx.x;
    int q = tid & 63, quad = tid >> 6;
    int iq = qc * 64 + q;
    int h = iq >> 5, w = iq & 31;

    const float* qp = qbuf + (bn * 1024 + iq) * 8;
    float4 qa = *(const float4*)qp;
    float4 qb = *(const float4*)(qp + 4);

    // Fill tables: thread (q, quad) computes rows t = quad*8 .. quad*8+7.
    #pragma unroll
    for (int i = 0; i < 8; ++i) {
        int t = quad * 8 + i;
        const float* rw = relw + (t - w + 31) * 8;
        lAw[t * 64 + q] =
            qa.x * rw[0] + qa.y * rw[1] + qa.z * rw[2] + qa.w * rw[3] +
            qb.x * rw[4] + qb.y * rw[5] + qb.z * rw[6] + qb.w * rw[7];
        const float* rh = relh + (t - h + 31) * 8;
        lAh[t * 64 + q] =
            qa.x * rh[0] + qa.y * rh[1] + qa.z * rh[2] + qa.w * rh[3] +
            qb.x * rh[4] + qb.y * rh[5] + qb.z * rh[6] + qb.w * rh[7];
    }
    __syncthreads();

    float a0 = 0.f, a1 = 0.f, a2 = 0.f, a3 = 0.f;
    float a4 = 0.f, a5 = 0.f, a6 = 0.f, a7 = 0.f;
    float l = 0.f;
    const float* kv = kvbuf + bn * (1024 * 16) + quad * (256 * 16);

    for (int j2 = 0; j2 < 8; ++j2) {       // h2 rows of this quarter
        float ah = lAh[(quad * 8 + j2) * 64 + q];
        const float* kvr = kv + j2 * (32 * 16);
        #pragma unroll 4
        for (int j1 = 0; j1 < 32; ++j1) {  // w2 within row
            const float* row = kvr + j1 * 16;   // wave-uniform
            float4 ka = *(const float4*)row;
            float4 kb = *(const float4*)(row + 4);
            float s = lAw[j1 * 64 + q] + ah;
            s += qa.x * ka.x + qa.y * ka.y + qa.z * ka.z + qa.w * ka.w +
                 qb.x * kb.x + qb.y * kb.y + qb.z * kb.z + qb.w * kb.w;
            float pe = __expf(s);
            l += pe;
            float4 va = *(const float4*)(row + 8);
            float4 vb = *(const float4*)(row + 12);
            a0 = fmaf(pe, va.x, a0); a1 = fmaf(pe, va.y, a1);
            a2 = fmaf(pe, va.z, a2); a3 = fmaf(pe, va.w, a3);
            a4 = fmaf(pe, vb.x, a4); a5 = fmaf(pe, vb.y, a5);
            a6 = fmaf(pe, vb.z, a6); a7 = fmaf(pe, vb.w, a7);
        }
    }

    red[0 * 256 + tid] = a0; red[1 * 256 + tid] = a1;
    red[2 * 256 + tid] = a2; red[3 * 256 + tid] = a3;
    red[4 * 256 + tid] = a4; red[5 * 256 + tid] = a5;
    red[6 * 256 + tid] = a6; red[7 * 256 + tid] = a7;
    red[8 * 256 + tid] = l;
    __syncthreads();

    if (tid < 64) {
        int b = bn >> 3, n = bn & 7;
        float li = red[8 * 256 + q] + red[8 * 256 + q + 64] +
                   red[8 * 256 + q + 128] + red[8 * 256 + q + 192];
        float inv = 1.0f / li;
        float* ap = apre + (b * 64 + n * 8) * 1024 + qc * 64 + q;
        #pragma unroll
        for (int d = 0; d < 8; ++d) {
            float av = red[d * 256 + q] + red[d * 256 + q + 64] +
                       red[d * 256 + q + 128] + red[d * 256 + q + 192];
            ap[d * 1024] = av * inv;
        }
    }
}

// ---------------------------------------------------------------------------
// Kernel 3: fused output (f32). grid = 8(b) x 4(row group) x 24(role) = 768:
// role 0..15  -> 3x3 conv, output channels role*4 .. role*4+3
// role 16..23 -> attn 1x1 projection, channels 64+(role-16)*8 ...
// Decode: rem/24 and rem%24 (NOT shifts -- 24 roles, R4 crash was og&31).
// ---------------------------------------------------------------------------
__global__ __launch_bounds__(256) void k_out(
    const float* __restrict__ xpad,
    const float* __restrict__ wconv,
    const float* __restrict__ bconv,
    const float* __restrict__ wattn,
    const float* __restrict__ battn,
    const float* __restrict__ apre,
    float* __restrict__ out)
{
    int blk = blockIdx.x;
    int b = blk / 96, rem = blk % 96, rg = rem / 24, og = rem % 24;
    int tid = threadIdx.x;
    int p = rg * 256 + tid;                 // 0..1023

    if (og < 16) {
        int oc0 = og * 4;
        float acc[4];
        #pragma unroll
        for (int g = 0; g < 4; ++g) acc[g] = bconv[oc0 + g];
        int row = p >> 5, col = p & 31;
        const float* xb = xpad + b * 64 * 1156 + row * 34 + col;
        for (int c = 0; c < 64; ++c) {
            const float* xc = xb + c * 1156;
            float xv[9];
            #pragma unroll
            for (int t = 0; t < 9; ++t) xv[t] = xc[(t / 3) * 34 + (t % 3)];
            const float* wc = wconv + (oc0 * 64 + c) * 9;   // uniform -> s_load
            #pragma unroll
            for (int g = 0; g < 4; ++g) {
                #pragma unroll
                for (int t = 0; t < 9; ++t)
                    acc[g] = fmaf(wc[g * 576 + t], xv[t], acc[g]);
            }
        }
        #pragma unroll
        for (int g = 0; g < 4; ++g)
            out[(b * 128 + oc0 + g) * 1024 + p] = acc[g];
    } else {
        int o0 = (og - 16) * 8;
        float acc[8];
        #pragma unroll
        for (int g = 0; g < 8; ++g) acc[g] = battn[o0 + g];
        const float* ap = apre + b * 64 * 1024 + p;
        for (int c = 0; c < 64; ++c) {
            float xv = ap[c * 1024];
            #pragma unroll
            for (int g = 0; g < 8; ++g)
                acc[g] = fmaf(wattn[(o0 + g) * 64 + c], xv, acc[g]);
        }
        #pragma unroll
        for (int g = 0; g < 8; ++g)
            out[(b * 128 + 64 + o0 + g) * 1024 + p] = acc[g];
    }
}

// ---------------------------------------------------------------------------
extern "C" void kernel_launch(void* const* d_in, const int* in_sizes, int n_in,
                              void* d_out, int out_size, void* d_ws, size_t ws_size,
                              hipStream_t stream)
{
    float* ws = (float*)d_ws;
    float* out = (float*)d_out;

    k_prep<<<(WEND + 255) / 256, 256, 0, stream>>>(
        d_in[0], d_in[1], d_in[2], d_in[3], d_in[4],
        d_in[5], d_in[6], d_in[7], d_in[8], ws);
    k_qkv<<<512, 256, 0, stream>>>(
        ws + XPAD, ws + WQKV, ws + BQKV, ws + QBUF, ws + KVBUF);
    k_attn<<<1024, 256, 0, stream>>>(
        ws + QBUF, ws + KVBUF, ws + RELW, ws + RELH, ws + APRE);
    k_out<<<768, 256, 0, stream>>>(
        ws + XPAD, ws + WCONV, ws + BCONV, ws + WATTN, ws + BATTN, ws + APRE, out);
}

// Round 6
// 258.212 us; speedup vs baseline: 1.1093x; 1.0037x over previous
//
#include <hip/hip_runtime.h>
#include <hip/hip_bf16.h>

// Problem constants: B=8, IN_C=64, H=W=32, NH=8, dkh=dvh=8, OUT_C=128.
// Inputs: float32 storage (verified R1/R2). Output: float32.
//
// R5->R6: k_attn KV loads were compiled to s_load (uniform addr + readonly
// restrict) -> SQC-miss serialized (dur invariant under 1.5x occupancy,
// SGPR=112/VGPR=44). Launder KV base through v_mov inline asm so the address
// is formally divergent -> global_load_dwordx4 vector path (same-address
// lanes = 1 line/instr broadcast via L1).

// ---- workspace layout (float32 element offsets) ----
constexpr int XPAD  = 0;                       // padded x: [8][64][34][34]
constexpr int NXPAD = 8 * 64 * 34 * 34;        // 591872
constexpr int WQKV  = NXPAD;                   // [192][64]        12288
constexpr int WCONV = WQKV + 12288;            // [64][64][9]      36864
constexpr int WATTN = WCONV + 36864;           // [64][64]          4096
constexpr int BQKV  = WATTN + 4096;            // 192
constexpr int BCONV = BQKV + 192;              // 64
constexpr int BATTN = BCONV + 64;              // 64
constexpr int RELW  = BATTN + 64;              // [63][8]           504
constexpr int RELH  = RELW + 504;              // [63][8]           504
constexpr int WEND  = RELH + 504;              // 646448
constexpr int QBUF  = WEND;                    // [64 bn][1024][8]  (q pre-scaled)
constexpr int KVBUF = QBUF + 524288;           // [64 bn][1024][16] (k|v interleaved)
constexpr int APRE  = KVBUF + 1048576;         // [8][64][1024]
// total = 2743600 floats = ~10.5 MB

__device__ __forceinline__ float load_in(const void* p, int i, bool f32mode) {
    return f32mode ? ((const float*)p)[i]
                   : __bfloat162float(((const __hip_bfloat16*)p)[i]);
}

// Returns 0 in a VGPR the compiler cannot prove uniform -> forces vector
// global loads (defeats s_load scalarization of uniform addresses).
__device__ __forceinline__ int lane_zero() {
    int v;
    asm volatile("v_mov_b32 %0, 0" : "=v"(v));
    return v;
}

// ---------------------------------------------------------------------------
// Kernel 0: upcast all params to f32 in ws; build zero-padded f32 x.
// ---------------------------------------------------------------------------
__global__ __launch_bounds__(256) void k_prep(
    const void* __restrict__ x,
    const void* __restrict__ conv_w,
    const void* __restrict__ conv_b,
    const void* __restrict__ qkv_w,
    const void* __restrict__ qkv_b,
    const void* __restrict__ attn_w,
    const void* __restrict__ attn_b,
    const void* __restrict__ rel_w,
    const void* __restrict__ rel_h,
    float* __restrict__ ws)
{
    // Storage-dtype sniff (hedge): f32 storage decoded as bf16 gives huge values.
    const __hip_bfloat16* xh = (const __hip_bfloat16*)x;
    bool f32mode = false;
    #pragma unroll
    for (int i = 0; i < 128; ++i) {
        float v = __bfloat162float(xh[i]);
        if (v > 1e3f || v < -1e3f) f32mode = true;
    }

    int idx = blockIdx.x * 256 + threadIdx.x;
    if (idx < NXPAD) {
        int bc = idx / 1156, r = idx % 1156;
        int hh = r / 34 - 1, ww = r % 34 - 1;
        float v = 0.f;
        if ((unsigned)hh < 32u && (unsigned)ww < 32u)
            v = load_in(x, bc * 1024 + hh * 32 + ww, f32mode);
        ws[XPAD + idx] = v;
    } else if (idx < WEND) {
        int w1 = idx - NXPAD;
        float v; int dst;
        if      (w1 < 12288) { v = load_in(qkv_w,  w1,          f32mode); dst = WQKV  + w1; }
        else if (w1 < 49152) { v = load_in(conv_w, w1 - 12288,  f32mode); dst = WCONV + w1 - 12288; }
        else if (w1 < 53248) { v = load_in(attn_w, w1 - 49152,  f32mode); dst = WATTN + w1 - 49152; }
        else if (w1 < 53440) { v = load_in(qkv_b,  w1 - 53248,  f32mode); dst = BQKV  + w1 - 53248; }
        else if (w1 < 53504) { v = load_in(conv_b, w1 - 53440,  f32mode); dst = BCONV + w1 - 53440; }
        else if (w1 < 53568) { v = load_in(attn_b, w1 - 53504,  f32mode); dst = BATTN + w1 - 53504; }
        else if (w1 < 54072) { v = load_in(rel_w,  w1 - 53568,  f32mode); dst = RELW  + w1 - 53568; }
        else                 { v = load_in(rel_h,  w1 - 54072,  f32mode); dst = RELH  + w1 - 54072; }
        ws[dst] = v;
    }
}

// ---------------------------------------------------------------------------
// Kernel 1: qkv 1x1 conv. grid = 8(b) x 4(pos chunk) x 16(out group of 12)
// = 512 blocks (2/CU). Weights wave-uniform (small, SQC-resident); x row in
// VGPRs.
// ---------------------------------------------------------------------------
__global__ __launch_bounds__(256) void k_qkv(
    const float* __restrict__ xpad,
    const float* __restrict__ wq,
    const float* __restrict__ bq,
    float* __restrict__ qbuf,
    float* __restrict__ kvbuf)
{
    int blk = blockIdx.x;
    int b = blk >> 6, rem = blk & 63, pc = rem >> 4, og = rem & 15;
    int p = pc * 256 + threadIdx.x;        // 0..1023
    int h = p >> 5, w = p & 31;
    const float* xb = xpad + (b * 64) * 1156 + (h + 1) * 34 + (w + 1);
    float xr[64];
    #pragma unroll
    for (int c = 0; c < 64; ++c) xr[c] = xb[c * 1156];

    #pragma unroll 4
    for (int oo = 0; oo < 12; ++oo) {
        int o = og * 12 + oo;              // 0..191, wave-uniform
        const float* wr = wq + o * 64;
        float acc = bq[o];
        #pragma unroll
        for (int c = 0; c < 64; ++c) acc = fmaf(wr[c], xr[c], acc);
        if (o < 64) {
            qbuf[((b * 8 + (o >> 3)) * 1024 + p) * 8 + (o & 7)] = acc * 0.35355339059327373f;
        } else if (o < 128) {
            int k = o - 64;
            kvbuf[((b * 8 + (k >> 3)) * 1024 + p) * 16 + (k & 7)] = acc;
        } else {
            int k = o - 128;
            kvbuf[((b * 8 + (k >> 3)) * 1024 + p) * 16 + 8 + (k & 7)] = acc;
        }
    }
}

// ---------------------------------------------------------------------------
// Kernel 2: attention. grid = 64(bn) x 16(query chunk of 64) = 1024 blocks.
// 256 threads: tid = q(0..63) + 64*quad(0..3); quads split the 1024 keys into
// 256-key quarters (wave == quad -> all lanes read the SAME KV row).
// KV base laundered via lane_zero() so those reads stay on the vector memory
// pipe (global_load_dwordx4, 1 line/instr broadcast) instead of s_load/SQC.
// Aw/Ah tables dedup'd per query: [32][64] each; 25 KB LDS total.
// No-max softmax (logits O(+-3)) -> quad partials merge by plain sum.
// ---------------------------------------------------------------------------
__global__ __launch_bounds__(256) void k_attn(
    const float* __restrict__ qbuf,
    const float* __restrict__ kvbuf,
    const float* __restrict__ relw,
    const float* __restrict__ relh,
    float* __restrict__ apre)
{
    __shared__ float lAw[32 * 64];
    __shared__ float lAh[32 * 64];
    __shared__ float red[9 * 256];

    int blk = blockIdx.x;
    int bn = blk >> 4, qc = blk & 15;
    int tid = threadIdx.x;
    int q = tid & 63, quad = tid >> 6;
    int iq = qc * 64 + q;
    int h = iq >> 5, w = iq & 31;

    const float* qp = qbuf + (bn * 1024 + iq) * 8;
    float4 qa = *(const float4*)qp;
    float4 qb = *(const float4*)(qp + 4);

    // Fill tables: thread (q, quad) computes rows t = quad*8 .. quad*8+7.
    #pragma unroll
    for (int i = 0; i < 8; ++i) {
        int t = quad * 8 + i;
        const float* rw = relw + (t - w + 31) * 8;
        lAw[t * 64 + q] =
            qa.x * rw[0] + qa.y * rw[1] + qa.z * rw[2] + qa.w * rw[3] +
            qb.x * rw[4] + qb.y * rw[5] + qb.z * rw[6] + qb.w * rw[7];
        const float* rh = relh + (t - h + 31) * 8;
        lAh[t * 64 + q] =
            qa.x * rh[0] + qa.y * rh[1] + qa.z * rh[2] + qa.w * rh[3] +
            qb.x * rh[4] + qb.y * rh[5] + qb.z * rh[6] + qb.w * rh[7];
    }
    __syncthreads();

    float a0 = 0.f, a1 = 0.f, a2 = 0.f, a3 = 0.f;
    float a4 = 0.f, a5 = 0.f, a6 = 0.f, a7 = 0.f;
    float l = 0.f;
    // Laundered base: address is formally divergent -> vector loads.
    const float* kv = kvbuf + bn * (1024 * 16) + quad * (256 * 16) + lane_zero();

    for (int j2 = 0; j2 < 8; ++j2) {       // h2 rows of this quarter
        float ah = lAh[(quad * 8 + j2) * 64 + q];
        const float* kvr = kv + j2 * (32 * 16);
        #pragma unroll 4
        for (int j1 = 0; j1 < 32; ++j1) {  // w2 within row
            const float* row = kvr + j1 * 16;   // same addr on all lanes
            float4 ka = *(const float4*)row;
            float4 kb = *(const float4*)(row + 4);
            float s = lAw[j1 * 64 + q] + ah;
            s += qa.x * ka.x + qa.y * ka.y + qa.z * ka.z + qa.w * ka.w +
                 qb.x * kb.x + qb.y * kb.y + qb.z * kb.z + qb.w * kb.w;
            float pe = __expf(s);
            l += pe;
            float4 va = *(const float4*)(row + 8);
            float4 vb = *(const float4*)(row + 12);
            a0 = fmaf(pe, va.x, a0); a1 = fmaf(pe, va.y, a1);
            a2 = fmaf(pe, va.z, a2); a3 = fmaf(pe, va.w, a3);
            a4 = fmaf(pe, vb.x, a4); a5 = fmaf(pe, vb.y, a5);
            a6 = fmaf(pe, vb.z, a6); a7 = fmaf(pe, vb.w, a7);
        }
    }

    red[0 * 256 + tid] = a0; red[1 * 256 + tid] = a1;
    red[2 * 256 + tid] = a2; red[3 * 256 + tid] = a3;
    red[4 * 256 + tid] = a4; red[5 * 256 + tid] = a5;
    red[6 * 256 + tid] = a6; red[7 * 256 + tid] = a7;
    red[8 * 256 + tid] = l;
    __syncthreads();

    if (tid < 64) {
        int b = bn >> 3, n = bn & 7;
        float li = red[8 * 256 + q] + red[8 * 256 + q + 64] +
                   red[8 * 256 + q + 128] + red[8 * 256 + q + 192];
        float inv = 1.0f / li;
        float* ap = apre + (b * 64 + n * 8) * 1024 + qc * 64 + q;
        #pragma unroll
        for (int d = 0; d < 8; ++d) {
            float av = red[d * 256 + q] + red[d * 256 + q + 64] +
                       red[d * 256 + q + 128] + red[d * 256 + q + 192];
            ap[d * 1024] = av * inv;
        }
    }
}

// ---------------------------------------------------------------------------
// Kernel 3: fused output (f32). grid = 8(b) x 4(row group) x 24(role) = 768:
// role 0..15  -> 3x3 conv, output channels role*4 .. role*4+3
// role 16..23 -> attn 1x1 projection, channels 64+(role-16)*8 ...
// Decode: rem/24 and rem%24 (NOT shifts -- 24 roles, R4 crash was og&31).
// ---------------------------------------------------------------------------
__global__ __launch_bounds__(256) void k_out(
    const float* __restrict__ xpad,
    const float* __restrict__ wconv,
    const float* __restrict__ bconv,
    const float* __restrict__ wattn,
    const float* __restrict__ battn,
    const float* __restrict__ apre,
    float* __restrict__ out)
{
    int blk = blockIdx.x;
    int b = blk / 96, rem = blk % 96, rg = rem / 24, og = rem % 24;
    int tid = threadIdx.x;
    int p = rg * 256 + tid;                 // 0..1023

    if (og < 16) {
        int oc0 = og * 4;
        float acc[4];
        #pragma unroll
        for (int g = 0; g < 4; ++g) acc[g] = bconv[oc0 + g];
        int row = p >> 5, col = p & 31;
        const float* xb = xpad + b * 64 * 1156 + row * 34 + col;
        for (int c = 0; c < 64; ++c) {
            const float* xc = xb + c * 1156;
            float xv[9];
            #pragma unroll
            for (int t = 0; t < 9; ++t) xv[t] = xc[(t / 3) * 34 + (t % 3)];
            const float* wc = wconv + (oc0 * 64 + c) * 9;   // uniform, SQC-hot
            #pragma unroll
            for (int g = 0; g < 4; ++g) {
                #pragma unroll
                for (int t = 0; t < 9; ++t)
                    acc[g] = fmaf(wc[g * 576 + t], xv[t], acc[g]);
            }
        }
        #pragma unroll
        for (int g = 0; g < 4; ++g)
            out[(b * 128 + oc0 + g) * 1024 + p] = acc[g];
    } else {
        int o0 = (og - 16) * 8;
        float acc[8];
        #pragma unroll
        for (int g = 0; g < 8; ++g) acc[g] = battn[o0 + g];
        const float* ap = apre + b * 64 * 1024 + p;
        for (int c = 0; c < 64; ++c) {
            float xv = ap[c * 1024];
            #pragma unroll
            for (int g = 0; g < 8; ++g)
                acc[g] = fmaf(wattn[(o0 + g) * 64 + c], xv, acc[g]);
        }
        #pragma unroll
        for (int g = 0; g < 8; ++g)
            out[(b * 128 + 64 + o0 + g) * 1024 + p] = acc[g];
    }
}

// ---------------------------------------------------------------------------
extern "C" void kernel_launch(void* const* d_in, const int* in_sizes, int n_in,
                              void* d_out, int out_size, void* d_ws, size_t ws_size,
                              hipStream_t stream)
{
    float* ws = (float*)d_ws;
    float* out = (float*)d_out;

    k_prep<<<(WEND + 255) / 256, 256, 0, stream>>>(
        d_in[0], d_in[1], d_in[2], d_in[3], d_in[4],
        d_in[5], d_in[6], d_in[7], d_in[8], ws);
    k_qkv<<<512, 256, 0, stream>>>(
        ws + XPAD, ws + WQKV, ws + BQKV, ws + QBUF, ws + KVBUF);
    k_attn<<<1024, 256, 0, stream>>>(
        ws + QBUF, ws + KVBUF, ws + RELW, ws + RELH, ws + APRE);
    k_out<<<768, 256, 0, stream>>>(
        ws + XPAD, ws + WCONV, ws + BCONV, ws + WATTN, ws + BATTN, ws + APRE, out);
}

// Round 7
// 178.092 us; speedup vs baseline: 1.6084x; 1.4499x over previous
//
#include <hip/hip_runtime.h>
#include <hip/hip_bf16.h>

// Problem constants: B=8, IN_C=64, H=W=32, NH=8, dkh=dvh=8, OUT_C=128.
// Inputs: float32 storage (verified R1/R2). Output: float32.
//
// R6->R7: uniform-address global loads in hot loops cost ~20 cyc/instr of
// per-CU address processing regardless of occupancy (dur invariant R3/R5/R6).
// All hot kernels now use coalesced global->LDS staging + LDS broadcast reads.

// ---- workspace layout (float32 element offsets) ----
constexpr int XPAD  = 0;                       // padded x: [8][64][34][34]
constexpr int NXPAD = 8 * 64 * 34 * 34;        // 591872
constexpr int WQKV  = NXPAD;                   // [192][64]        12288
constexpr int WCONV = WQKV + 12288;            // [64][64][9]      36864
constexpr int WATTN = WCONV + 36864;           // [64][64]          4096
constexpr int BQKV  = WATTN + 4096;            // 192
constexpr int BCONV = BQKV + 192;              // 64
constexpr int BATTN = BCONV + 64;              // 64
constexpr int RELW  = BATTN + 64;              // [63][8]           504
constexpr int RELH  = RELW + 504;              // [63][8]           504
constexpr int WEND  = RELH + 504;              // 646448
constexpr int QBUF  = WEND;                    // [64 bn][1024][8]  (q pre-scaled)
constexpr int KVBUF = QBUF + 524288;           // [64 bn][1024][16] (k|v interleaved)
constexpr int APRE  = KVBUF + 1048576;         // [8][64][1024]
// total = 2743600 floats = ~10.5 MB

__device__ __forceinline__ float load_in(const void* p, int i, bool f32mode) {
    return f32mode ? ((const float*)p)[i]
                   : __bfloat162float(((const __hip_bfloat16*)p)[i]);
}

__device__ __forceinline__ float dot8(float4 a, float4 b, const float* r) {
    return a.x*r[0] + a.y*r[1] + a.z*r[2] + a.w*r[3] +
           b.x*r[4] + b.y*r[5] + b.z*r[6] + b.w*r[7];
}

// ---------------------------------------------------------------------------
// Kernel 0: upcast all params to f32 in ws; build zero-padded f32 x.
// ---------------------------------------------------------------------------
__global__ __launch_bounds__(256) void k_prep(
    const void* __restrict__ x,
    const void* __restrict__ conv_w,
    const void* __restrict__ conv_b,
    const void* __restrict__ qkv_w,
    const void* __restrict__ qkv_b,
    const void* __restrict__ attn_w,
    const void* __restrict__ attn_b,
    const void* __restrict__ rel_w,
    const void* __restrict__ rel_h,
    float* __restrict__ ws)
{
    // Storage-dtype sniff (hedge): f32 storage decoded as bf16 gives huge values.
    const __hip_bfloat16* xh = (const __hip_bfloat16*)x;
    bool f32mode = false;
    #pragma unroll
    for (int i = 0; i < 128; ++i) {
        float v = __bfloat162float(xh[i]);
        if (v > 1e3f || v < -1e3f) f32mode = true;
    }

    int idx = blockIdx.x * 256 + threadIdx.x;
    if (idx < NXPAD) {
        int bc = idx / 1156, r = idx % 1156;
        int hh = r / 34 - 1, ww = r % 34 - 1;
        float v = 0.f;
        if ((unsigned)hh < 32u && (unsigned)ww < 32u)
            v = load_in(x, bc * 1024 + hh * 32 + ww, f32mode);
        ws[XPAD + idx] = v;
    } else if (idx < WEND) {
        int w1 = idx - NXPAD;
        float v; int dst;
        if      (w1 < 12288) { v = load_in(qkv_w,  w1,          f32mode); dst = WQKV  + w1; }
        else if (w1 < 49152) { v = load_in(conv_w, w1 - 12288,  f32mode); dst = WCONV + w1 - 12288; }
        else if (w1 < 53248) { v = load_in(attn_w, w1 - 49152,  f32mode); dst = WATTN + w1 - 49152; }
        else if (w1 < 53440) { v = load_in(qkv_b,  w1 - 53248,  f32mode); dst = BQKV  + w1 - 53248; }
        else if (w1 < 53504) { v = load_in(conv_b, w1 - 53440,  f32mode); dst = BCONV + w1 - 53440; }
        else if (w1 < 53568) { v = load_in(attn_b, w1 - 53504,  f32mode); dst = BATTN + w1 - 53504; }
        else if (w1 < 54072) { v = load_in(rel_w,  w1 - 53568,  f32mode); dst = RELW  + w1 - 53568; }
        else                 { v = load_in(rel_h,  w1 - 54072,  f32mode); dst = RELH  + w1 - 54072; }
        ws[dst] = v;
    }
}

// ---------------------------------------------------------------------------
// Kernel 1: qkv 1x1 conv. grid = 8(b) x 4(pos chunk) x 16(out group of 12)
// = 512 blocks. Weight rows staged to LDS (coalesced), read as b128 broadcast.
// ---------------------------------------------------------------------------
__global__ __launch_bounds__(256) void k_qkv(
    const float* __restrict__ xpad,
    const float* __restrict__ wq,
    const float* __restrict__ bq,
    float* __restrict__ qbuf,
    float* __restrict__ kvbuf)
{
    __shared__ __align__(16) float4 wl4[192];   // 12 rows x 16 float4
    __shared__ float bl[12];

    int blk = blockIdx.x;
    int b = blk >> 6, rem = blk & 63, pc = rem >> 4, og = rem & 15;
    int tid = threadIdx.x;

    if (tid < 192) wl4[tid] = ((const float4*)(wq + og * 768))[tid];
    if (tid < 12)  bl[tid] = bq[og * 12 + tid];

    int p = pc * 256 + tid;                // 0..1023
    int h = p >> 5, w = p & 31;
    const float* xb = xpad + (b * 64) * 1156 + (h + 1) * 34 + (w + 1);
    float xr[64];
    #pragma unroll
    for (int c = 0; c < 64; ++c) xr[c] = xb[c * 1156];

    __syncthreads();

    #pragma unroll 4
    for (int oo = 0; oo < 12; ++oo) {
        int o = og * 12 + oo;              // 0..191
        float acc = bl[oo];
        #pragma unroll
        for (int c4 = 0; c4 < 16; ++c4) {
            float4 wv = wl4[oo * 16 + c4]; // uniform addr -> LDS broadcast
            acc = fmaf(wv.x, xr[c4 * 4 + 0], acc);
            acc = fmaf(wv.y, xr[c4 * 4 + 1], acc);
            acc = fmaf(wv.z, xr[c4 * 4 + 2], acc);
            acc = fmaf(wv.w, xr[c4 * 4 + 3], acc);
        }
        if (o < 64) {
            qbuf[((b * 8 + (o >> 3)) * 1024 + p) * 8 + (o & 7)] = acc * 0.35355339059327373f;
        } else if (o < 128) {
            int k = o - 64;
            kvbuf[((b * 8 + (k >> 3)) * 1024 + p) * 16 + (k & 7)] = acc;
        } else {
            int k = o - 128;
            kvbuf[((b * 8 + (k >> 3)) * 1024 + p) * 16 + 8 + (k & 7)] = acc;
        }
    }
}

// ---------------------------------------------------------------------------
// Kernel 2: attention. grid = 64(bn) x 8(query chunk of 128) = 512 blocks,
// 256 thr. Thread (lane, quad) handles queries {iq0=qc*128+lane, iq1=iq0+64};
// wave quad owns key quarter [quad*256, +256). Each wave stages its 32-key
// chunk (2 KB) into private LDS via 2 coalesced dwordx4 loads/lane with
// register prefetch; no barriers in the main loop (same-wave DS ordering).
// j2 is constant within a chunk -> Ah computed on the fly (2x dot8/chunk);
// lAw[32 w2][128 q] in LDS (stride-1 reads). No-max softmax; quad partials
// merged via LDS after the loop.
// ---------------------------------------------------------------------------
__global__ __launch_bounds__(256) void k_attn(
    const float* __restrict__ qbuf,
    const float* __restrict__ kvbuf,
    const float* __restrict__ relw,
    const float* __restrict__ relh,
    float* __restrict__ apre)
{
    // [0,4096): lAw[32][128]; [4096,6144): stage[4 waves][512]
    // after main loop: [0,4608) reused as reduction buffer
    __shared__ __align__(16) float smem[6144];

    int tid = threadIdx.x;
    int lane = tid & 63, quad = tid >> 6;
    int bn = blockIdx.x >> 3, qcv = blockIdx.x & 7;

    // ---- fill lAw: thread covers query qi = tid&127, rows (tid>>7)*16.. ----
    {
        int qi = tid & 127;
        int r0 = (tid >> 7) * 16;
        int iqf = qcv * 128 + qi;
        int wf = iqf & 31;
        const float* qpf = qbuf + (bn * 1024 + iqf) * 8;
        float4 fa = *(const float4*)qpf;
        float4 fb = *(const float4*)(qpf + 4);
        #pragma unroll
        for (int r = r0; r < r0 + 16; ++r)
            smem[r * 128 + qi] = dot8(fa, fb, relw + (r - wf + 31) * 8);
    }

    int iq0 = qcv * 128 + lane;
    int iq1 = iq0 + 64;
    int h0 = iq0 >> 5, h1 = iq1 >> 5;
    const float* qp0 = qbuf + (bn * 1024 + iq0) * 8;
    const float* qp1 = qbuf + (bn * 1024 + iq1) * 8;
    float4 q0a = *(const float4*)qp0, q0b = *(const float4*)(qp0 + 4);
    float4 q1a = *(const float4*)qp1, q1b = *(const float4*)(qp1 + 4);

    __syncthreads();

    float acc0[8] = {0,0,0,0,0,0,0,0};
    float acc1[8] = {0,0,0,0,0,0,0,0};
    float l0 = 0.f, l1 = 0.f;

    const float4* gkv = (const float4*)(kvbuf + bn * 16384 + quad * 4096);
    float* stg = smem + 4096 + quad * 512;   // this wave's private stage
    float4 p0 = gkv[lane];
    float4 p1 = gkv[64 + lane];

    for (int c = 0; c < 8; ++c) {
        ((float4*)stg)[lane] = p0;           // coalesced ds_write_b128
        ((float4*)stg)[64 + lane] = p1;
        if (c < 7) {                         // prefetch next chunk into regs
            p0 = gkv[(c + 1) * 128 + lane];
            p1 = gkv[(c + 1) * 128 + 64 + lane];
        }
        int t = quad * 8 + c;                // j2 row (constant per chunk)
        float ah0 = dot8(q0a, q0b, relh + (t - h0 + 31) * 8);
        float ah1 = dot8(q1a, q1b, relh + (t - h1 + 31) * 8);

        #pragma unroll 4
        for (int r = 0; r < 32; ++r) {
            const float4* row = (const float4*)(stg + r * 16);
            float4 ka = row[0], kb = row[1];
            float4 va = row[2], vb = row[3];

            float s0 = smem[r * 128 + lane] + ah0 +
                q0a.x*ka.x + q0a.y*ka.y + q0a.z*ka.z + q0a.w*ka.w +
                q0b.x*kb.x + q0b.y*kb.y + q0b.z*kb.z + q0b.w*kb.w;
            float pe0 = __expf(s0);
            l0 += pe0;
            acc0[0] = fmaf(pe0, va.x, acc0[0]); acc0[1] = fmaf(pe0, va.y, acc0[1]);
            acc0[2] = fmaf(pe0, va.z, acc0[2]); acc0[3] = fmaf(pe0, va.w, acc0[3]);
            acc0[4] = fmaf(pe0, vb.x, acc0[4]); acc0[5] = fmaf(pe0, vb.y, acc0[5]);
            acc0[6] = fmaf(pe0, vb.z, acc0[6]); acc0[7] = fmaf(pe0, vb.w, acc0[7]);

            float s1 = smem[r * 128 + 64 + lane] + ah1 +
                q1a.x*ka.x + q1a.y*ka.y + q1a.z*ka.z + q1a.w*ka.w +
                q1b.x*kb.x + q1b.y*kb.y + q1b.z*kb.z + q1b.w*kb.w;
            float pe1 = __expf(s1);
            l1 += pe1;
            acc1[0] = fmaf(pe1, va.x, acc1[0]); acc1[1] = fmaf(pe1, va.y, acc1[1]);
            acc1[2] = fmaf(pe1, va.z, acc1[2]); acc1[3] = fmaf(pe1, va.w, acc1[3]);
            acc1[4] = fmaf(pe1, vb.x, acc1[4]); acc1[5] = fmaf(pe1, vb.y, acc1[5]);
            acc1[6] = fmaf(pe1, vb.z, acc1[6]); acc1[7] = fmaf(pe1, vb.w, acc1[7]);
        }
    }

    __syncthreads();   // all waves done with lAw/stage -> reuse as red buffer
    #pragma unroll
    for (int d = 0; d < 8; ++d) {
        smem[d * 256 + tid] = acc0[d];
        smem[(9 + d) * 256 + tid] = acc1[d];
    }
    smem[8 * 256 + tid] = l0;
    smem[17 * 256 + tid] = l1;
    __syncthreads();

    if (tid < 128) {
        int ln = tid & 63;
        int sb = (tid < 64) ? 0 : 9;
        float l = smem[(sb + 8) * 256 + ln]       + smem[(sb + 8) * 256 + ln + 64] +
                  smem[(sb + 8) * 256 + ln + 128] + smem[(sb + 8) * 256 + ln + 192];
        float inv = 1.0f / l;
        int b = bn >> 3, n = bn & 7;
        float* ap = apre + (b * 64 + n * 8) * 1024 + qcv * 128 + tid;
        #pragma unroll
        for (int d = 0; d < 8; ++d) {
            float av = smem[(sb + d) * 256 + ln]       + smem[(sb + d) * 256 + ln + 64] +
                       smem[(sb + d) * 256 + ln + 128] + smem[(sb + d) * 256 + ln + 192];
            ap[d * 1024] = av * inv;
        }
    }
}

// ---------------------------------------------------------------------------
// Kernel 3: fused output (f32). grid = 8(b) x 4(row group) x 24(role) = 768:
// role 0..15  -> 3x3 conv, oc role*4..+3.  Weights staged g-transposed
//   ([c*9+t][4g], b128 broadcast = 4 MACs); x staged in 16-channel LDS chunks.
// role 16..23 -> attn 1x1 proj, oc 64+(role-16)*8.. Weights staged c-transposed.
// Branch is block-uniform (og per-block) so barrier counts are consistent.
// ---------------------------------------------------------------------------
__global__ __launch_bounds__(256) void k_out(
    const float* __restrict__ xpad,
    const float* __restrict__ wconv,
    const float* __restrict__ bconv,
    const float* __restrict__ wattn,
    const float* __restrict__ battn,
    const float* __restrict__ apre,
    float* __restrict__ out)
{
    __shared__ __align__(16) float wl[2304];     // conv weights / attn weights
    __shared__ __align__(16) float xl[16 * 340]; // conv: 16-ch x-chunk
    __shared__ float bl[8];

    int blk = blockIdx.x;
    int b = blk / 96, rem = blk % 96, rg = rem / 24, og = rem % 24;
    int tid = threadIdx.x;
    int p = rg * 256 + tid;                 // 0..1023

    if (og < 16) {
        int oc0 = og * 4;
        // stage weights transposed: wl[(c*9+t)*4 + g] = wconv[(oc0+g)*576 + c*9+t]
        for (int i = tid; i < 2304; i += 256) {
            int g = i & 3, ct = i >> 2;
            wl[i] = wconv[(oc0 + g) * 576 + ct];
        }
        if (tid < 4) bl[tid] = bconv[oc0 + tid];

        float acc[4] = {0.f, 0.f, 0.f, 0.f};
        int lr = tid >> 5, col = tid & 31;  // local out row (0..7), col
        int r0 = rg * 8;
        const float* xsrc = xpad + b * 64 * 1156 + r0 * 34;

        for (int ch = 0; ch < 4; ++ch) {
            __syncthreads();                // prev readers done (+weights visible)
            for (int i = tid; i < 5440; i += 256) {
                int cc = i / 340, off = i % 340;
                xl[i] = xsrc[(ch * 16 + cc) * 1156 + off];
            }
            __syncthreads();
            for (int cc = 0; cc < 16; ++cc) {
                const float* xc = xl + cc * 340 + lr * 34 + col;
                float xv[9];
                #pragma unroll
                for (int t = 0; t < 9; ++t) xv[t] = xc[(t / 3) * 34 + (t % 3)];
                const float4* wc = (const float4*)(wl + (ch * 16 + cc) * 36);
                #pragma unroll
                for (int t = 0; t < 9; ++t) {
                    float4 wv = wc[t];      // broadcast b128: 4 oc weights
                    acc[0] = fmaf(wv.x, xv[t], acc[0]);
                    acc[1] = fmaf(wv.y, xv[t], acc[1]);
                    acc[2] = fmaf(wv.z, xv[t], acc[2]);
                    acc[3] = fmaf(wv.w, xv[t], acc[3]);
                }
            }
        }
        #pragma unroll
        for (int g = 0; g < 4; ++g)
            out[(b * 128 + oc0 + g) * 1024 + p] = acc[g] + bl[g];
    } else {
        int o0 = (og - 16) * 8;
        // stage transposed: wl[c*8+g] = wattn[(o0+g)*64 + c]
        for (int i = tid; i < 512; i += 256) {
            int g = i & 7, c = i >> 3;
            wl[c * 8 + g] = wattn[(o0 + g) * 64 + c];
        }
        if (tid < 8) bl[tid] = battn[o0 + tid];
        __syncthreads();

        float acc[8] = {0,0,0,0,0,0,0,0};
        const float* ap = apre + b * 65536 + p;
        #pragma unroll 4
        for (int c = 0; c < 64; ++c) {
            float xv = ap[c * 1024];
            const float4* wv4 = (const float4*)(wl + c * 8);
            float4 wa = wv4[0], wb = wv4[1];  // broadcast
            acc[0] = fmaf(wa.x, xv, acc[0]); acc[1] = fmaf(wa.y, xv, acc[1]);
            acc[2] = fmaf(wa.z, xv, acc[2]); acc[3] = fmaf(wa.w, xv, acc[3]);
            acc[4] = fmaf(wb.x, xv, acc[4]); acc[5] = fmaf(wb.y, xv, acc[5]);
            acc[6] = fmaf(wb.z, xv, acc[6]); acc[7] = fmaf(wb.w, xv, acc[7]);
        }
        #pragma unroll
        for (int g = 0; g < 8; ++g)
            out[(b * 128 + 64 + o0 + g) * 1024 + p] = acc[g] + bl[g];
    }
}

// ---------------------------------------------------------------------------
extern "C" void kernel_launch(void* const* d_in, const int* in_sizes, int n_in,
                              void* d_out, int out_size, void* d_ws, size_t ws_size,
                              hipStream_t stream)
{
    float* ws = (float*)d_ws;
    float* out = (float*)d_out;

    k_prep<<<(WEND + 255) / 256, 256, 0, stream>>>(
        d_in[0], d_in[1], d_in[2], d_in[3], d_in[4],
        d_in[5], d_in[6], d_in[7], d_in[8], ws);
    k_qkv<<<512, 256, 0, stream>>>(
        ws + XPAD, ws + WQKV, ws + BQKV, ws + QBUF, ws + KVBUF);
    k_attn<<<512, 256, 0, stream>>>(
        ws + QBUF, ws + KVBUF, ws + RELW, ws + RELH, ws + APRE);
    k_out<<<768, 256, 0, stream>>>(
        ws + XPAD, ws + WCONV, ws + BCONV, ws + WATTN, ws + BATTN, ws + APRE, out);
}